// Round 3
// baseline (1048.822 us; speedup 1.0000x reference)
//
#include <hip/hip_runtime.h>
#include <cstdint>
#include <cstddef>

#define T_TOKENS 8192
#define HID 1024
#define HID2 2048
#define NE 8

typedef unsigned short u16;
typedef unsigned int u32;
typedef __bf16 bf16x8 __attribute__((ext_vector_type(8)));
typedef float f32x4 __attribute__((ext_vector_type(4)));

__device__ __forceinline__ u16 f2bf(float f) {
    union { float f; u32 i; } x; x.f = f;
    u32 r = x.i + 0x7fffu + ((x.i >> 16) & 1u);   // RNE
    return (u16)(r >> 16);
}

// ---------------- router: one wave per token, full fp32 ----------------
__global__ __launch_bounds__(256) void router_kernel(
    const float* __restrict__ x, const float* __restrict__ rw,
    int* __restrict__ cnt, int* __restrict__ rowlist, float* __restrict__ wrow)
{
    int wave = threadIdx.x >> 6;
    int lane = threadIdx.x & 63;
    int t = blockIdx.x * 4 + wave;

    float xv[16];
    const float* xp = x + (size_t)t * HID + lane * 16;
#pragma unroll
    for (int q = 0; q < 4; q++) {
        float4 v = *(const float4*)(xp + q * 4);
        xv[q * 4 + 0] = v.x; xv[q * 4 + 1] = v.y;
        xv[q * 4 + 2] = v.z; xv[q * 4 + 3] = v.w;
    }

    float logit[NE];
#pragma unroll
    for (int e = 0; e < NE; e++) {
        const float* rp = rw + (size_t)e * HID + lane * 16;
        float acc = 0.f;
#pragma unroll
        for (int q = 0; q < 4; q++) {
            float4 v = *(const float4*)(rp + q * 4);
            acc += xv[q * 4 + 0] * v.x + xv[q * 4 + 1] * v.y
                 + xv[q * 4 + 2] * v.z + xv[q * 4 + 3] * v.w;
        }
#pragma unroll
        for (int off = 32; off; off >>= 1) acc += __shfl_xor(acc, off, 64);
        logit[e] = acc;
    }

    if (lane == 0) {
        float v0 = -1e30f; int i0 = 0;
#pragma unroll
        for (int e = 0; e < NE; e++) if (logit[e] > v0) { v0 = logit[e]; i0 = e; }
        float v1 = -1e30f; int i1 = 0;
#pragma unroll
        for (int e = 0; e < NE; e++) if (e != i0 && logit[e] > v1) { v1 = logit[e]; i1 = e; }
        float w0 = 1.0f / (1.0f + __expf(v1 - v0));
        float w1 = 1.0f - w0;
        int p0 = atomicAdd(&cnt[i0], 1);
        rowlist[i0 * T_TOKENS + p0] = t;
        wrow[i0 * T_TOKENS + p0] = w0;
        int p1 = atomicAdd(&cnt[i1], 1);
        rowlist[i1 * T_TOKENS + p1] = t;
        wrow[i1 * T_TOKENS + p1] = w1;
    }
}

// ---------------- offsets: exclusive scan over 8 counts ----------------
__global__ void offsets_kernel(const int* __restrict__ cnt, int* __restrict__ off)
{
    if (threadIdx.x == 0) {
        int s = 0;
        for (int e = 0; e < NE; e++) { off[e] = s; s += cnt[e]; }
    }
}

#define BM 128
#define BN 128
#define BK 64
#define LDK 72

// ---------------- grouped GEMM1: h = gelu(X_gather @ W1[e]) ----------------
// x fp32 [T][1024]; W1 fp32 [E][K=1024][N=2048] (n-contiguous).
// B transpose-staged to Bs[n][k'] with XOR swizzle k' = k ^ (((n>>3)&7)<<3).
__global__ __launch_bounds__(256) void gemm1_kernel(
    const float* __restrict__ x, const float* __restrict__ w1,
    const int* __restrict__ cnt, const int* __restrict__ off,
    const int* __restrict__ rowlist, u16* __restrict__ hbuf)
{
    int e = blockIdx.z;
    int n_e = cnt[e];
    int mt = blockIdx.x;
    if (mt * BM >= n_e) return;
    int nt = blockIdx.y;

    __shared__ u16 As[BM][LDK];
    __shared__ u16 Bs[BN][LDK];
    __shared__ int toks[BM];

    int tid = threadIdx.x;
    if (tid < BM) {
        int r = mt * BM + tid;
        toks[tid] = (r < n_e) ? rowlist[e * T_TOKENS + r] : 0;
    }
    __syncthreads();

    int wv = tid >> 6, lane = tid & 63;
    int wm = (wv & 1) * 64, wn = (wv >> 1) * 64;
    int l15 = lane & 15, l4 = lane >> 4;

    f32x4 acc[4][4];
#pragma unroll
    for (int i = 0; i < 4; i++)
#pragma unroll
        for (int j = 0; j < 4; j++) acc[i][j] = (f32x4){0.f, 0.f, 0.f, 0.f};

    const float* w1e = w1 + (size_t)e * HID * HID2 + nt * BN;   // + k*HID2 + n

    for (int kb = 0; kb < HID; kb += BK) {
        // A: gathered token rows fp32 -> bf16, k-contiguous
#pragma unroll
        for (int i = 0; i < 8; i++) {
            int idx = tid + i * 256;            // 0..2047
            int m = idx >> 4;                   // 0..127
            int kq = (idx & 15) * 4;            // 0..60
            float4 v = *(const float4*)(x + (size_t)toks[m] * HID + kb + kq);
            u16 p[4] = { f2bf(v.x), f2bf(v.y), f2bf(v.z), f2bf(v.w) };
            *(uint2*)&As[m][kq] = *(const uint2*)p;
        }
        // B: transpose-stage fp32 -> bf16 with XOR swizzle
#pragma unroll
        for (int i = 0; i < 8; i++) {
            int idx = tid + i * 256;            // 0..2047
            int k = idx >> 5;                   // 0..63
            int n0 = (idx & 31) * 4;            // 0..124
            float4 v = *(const float4*)(w1e + (size_t)(kb + k) * HID2 + n0);
            int kc = k ^ (((n0 >> 3) & 7) << 3);
            Bs[n0 + 0][kc] = f2bf(v.x);
            Bs[n0 + 1][kc] = f2bf(v.y);
            Bs[n0 + 2][kc] = f2bf(v.z);
            Bs[n0 + 3][kc] = f2bf(v.w);
        }
        __syncthreads();
#pragma unroll
        for (int ks = 0; ks < 2; ks++) {
            int kk = ks * 32 + l4 * 8;
            bf16x8 af[4], bfr[4];
#pragma unroll
            for (int i = 0; i < 4; i++) af[i] = *(const bf16x8*)&As[wm + i * 16 + l15][kk];
#pragma unroll
            for (int j = 0; j < 4; j++) {
                int n = wn + j * 16 + l15;
                bfr[j] = *(const bf16x8*)&Bs[n][kk ^ (((n >> 3) & 7) << 3)];
            }
#pragma unroll
            for (int i = 0; i < 4; i++)
#pragma unroll
                for (int j = 0; j < 4; j++)
                    acc[i][j] = __builtin_amdgcn_mfma_f32_16x16x32_bf16(af[i], bfr[j], acc[i][j], 0, 0, 0);
        }
        __syncthreads();
    }

    int base_row = off[e] + mt * BM;
#pragma unroll
    for (int i = 0; i < 4; i++) {
        int mlo = wm + i * 16 + l4 * 4;
#pragma unroll
        for (int j = 0; j < 4; j++) {
            int n = nt * BN + wn + j * 16 + l15;
#pragma unroll
            for (int rg = 0; rg < 4; rg++) {
                int m = mlo + rg;
                int r = mt * BM + m;
                if (r < n_e) {
                    float v = acc[i][j][rg];
                    float g = 0.5f * v * (1.0f + erff(v * 0.70710678118654752f));
                    hbuf[(size_t)(base_row + m) * HID2 + n] = f2bf(g);
                }
            }
        }
    }
}

// ---------------- grouped GEMM2: d_out += w * (H @ W2[e]) ----------------
// hbuf bf16 [rows][2048]; W2 fp32 [E][K=2048][N=1024] (n-contiguous).
__global__ __launch_bounds__(256) void gemm2_kernel(
    const u16* __restrict__ hbuf, const float* __restrict__ w2,
    const int* __restrict__ cnt, const int* __restrict__ off,
    const int* __restrict__ rowlist, const float* __restrict__ wrow,
    float* __restrict__ dout)
{
    int e = blockIdx.z;
    int n_e = cnt[e];
    int mt = blockIdx.x;
    if (mt * BM >= n_e) return;
    int nt = blockIdx.y;

    __shared__ u16 As[BM][LDK];
    __shared__ u16 Bs[BN][LDK];
    __shared__ int toks[BM];
    __shared__ float wts[BM];

    int tid = threadIdx.x;
    if (tid < BM) {
        int r = mt * BM + tid;
        toks[tid] = (r < n_e) ? rowlist[e * T_TOKENS + r] : 0;
        wts[tid] = (r < n_e) ? wrow[e * T_TOKENS + r] : 0.f;
    }
    __syncthreads();

    int wv = tid >> 6, lane = tid & 63;
    int wm = (wv & 1) * 64, wn = (wv >> 1) * 64;
    int l15 = lane & 15, l4 = lane >> 4;

    f32x4 acc[4][4];
#pragma unroll
    for (int i = 0; i < 4; i++)
#pragma unroll
        for (int j = 0; j < 4; j++) acc[i][j] = (f32x4){0.f, 0.f, 0.f, 0.f};

    const u16* hrow = hbuf + (size_t)(off[e] + mt * BM) * HID2;
    const float* w2e = w2 + (size_t)e * HID2 * HID + nt * BN;   // + k*HID + n

    for (int kb = 0; kb < HID2; kb += BK) {
        // A: bf16 rows of hbuf, 16B vector loads
#pragma unroll
        for (int i = 0; i < 4; i++) {
            int idx = tid + i * 256;            // 0..1023
            int m = idx >> 3;                   // 0..127
            int kk = (idx & 7) * 8;             // 0..56
            *(uint4*)&As[m][kk] = *(const uint4*)(hrow + (size_t)m * HID2 + kb + kk);
        }
        // B: transpose-stage fp32 -> bf16 with XOR swizzle
#pragma unroll
        for (int i = 0; i < 8; i++) {
            int idx = tid + i * 256;
            int k = idx >> 5;
            int n0 = (idx & 31) * 4;
            float4 v = *(const float4*)(w2e + (size_t)(kb + k) * HID + n0);
            int kc = k ^ (((n0 >> 3) & 7) << 3);
            Bs[n0 + 0][kc] = f2bf(v.x);
            Bs[n0 + 1][kc] = f2bf(v.y);
            Bs[n0 + 2][kc] = f2bf(v.z);
            Bs[n0 + 3][kc] = f2bf(v.w);
        }
        __syncthreads();
#pragma unroll
        for (int ks = 0; ks < 2; ks++) {
            int kk = ks * 32 + l4 * 8;
            bf16x8 af[4], bfr[4];
#pragma unroll
            for (int i = 0; i < 4; i++) af[i] = *(const bf16x8*)&As[wm + i * 16 + l15][kk];
#pragma unroll
            for (int j = 0; j < 4; j++) {
                int n = wn + j * 16 + l15;
                bfr[j] = *(const bf16x8*)&Bs[n][kk ^ (((n >> 3) & 7) << 3)];
            }
#pragma unroll
            for (int i = 0; i < 4; i++)
#pragma unroll
                for (int j = 0; j < 4; j++)
                    acc[i][j] = __builtin_amdgcn_mfma_f32_16x16x32_bf16(af[i], bfr[j], acc[i][j], 0, 0, 0);
        }
        __syncthreads();
    }

#pragma unroll
    for (int i = 0; i < 4; i++) {
        int mlo = wm + i * 16 + l4 * 4;
#pragma unroll
        for (int j = 0; j < 4; j++) {
            int n = nt * BN + wn + j * 16 + l15;
#pragma unroll
            for (int rg = 0; rg < 4; rg++) {
                int m = mlo + rg;
                int r = mt * BM + m;
                if (r < n_e) {
                    atomicAdd(&dout[(size_t)toks[m] * HID + n], acc[i][j][rg] * wts[m]);
                }
            }
        }
    }
}

extern "C" void kernel_launch(void* const* d_in, const int* in_sizes, int n_in,
                              void* d_out, int out_size, void* d_ws, size_t ws_size,
                              hipStream_t stream)
{
    const float* x  = (const float*)d_in[0];   // [8192][1024] fp32
    const float* rw = (const float*)d_in[1];   // [8][1024] fp32
    const float* w1 = (const float*)d_in[2];   // [8][1024][2048] fp32
    const float* w2 = (const float*)d_in[3];   // [8][2048][1024] fp32
    float* out = (float*)d_out;                // [8192][1024] fp32

    // Workspace: control arrays first, then bf16 hbuf. Total ~66 MiB.
    char* ws = (char*)d_ws;
    int*   cnt     = (int*)(ws + 0);
    int*   off     = (int*)(ws + 256);
    int*   rowlist = (int*)(ws + 512);                                  // 256 KB
    float* wrow    = (float*)(ws + 512 + (size_t)NE * T_TOKENS * 4);    // 256 KB
    u16*   hbuf    = (u16*)(ws + (1u << 20));                           // [16512][2048] bf16 = 64.5 MiB

    hipMemsetAsync(cnt, 0, 32, stream);
    hipMemsetAsync(out, 0, (size_t)T_TOKENS * HID * sizeof(float), stream);

    router_kernel<<<T_TOKENS / 4, 256, 0, stream>>>(x, rw, cnt, rowlist, wrow);
    offsets_kernel<<<1, 64, 0, stream>>>(cnt, off);

    gemm1_kernel<<<dim3(T_TOKENS / BM, HID2 / BN, NE), 256, 0, stream>>>(x, w1, cnt, off, rowlist, hbuf);
    gemm2_kernel<<<dim3(T_TOKENS / BM, HID / BN, NE), 256, 0, stream>>>(hbuf, w2, cnt, off, rowlist, wrow, out);
}

// Round 4
// 840.198 us; speedup vs baseline: 1.2483x; 1.2483x over previous
//
#include <hip/hip_runtime.h>
#include <cstdint>
#include <cstddef>

#define T_TOKENS 8192
#define HID 1024
#define HID2 2048
#define NE 8

typedef unsigned short u16;
typedef unsigned int u32;
typedef __bf16 bf16x8 __attribute__((ext_vector_type(8)));
typedef float f32x4 __attribute__((ext_vector_type(4)));

__device__ __forceinline__ u16 f2bf(float f) {
    union { float f; u32 i; } x; x.f = f;
    u32 r = x.i + 0x7fffu + ((x.i >> 16) & 1u);   // RNE
    return (u16)(r >> 16);
}

// ---------------- router: one wave per token, full fp32 ----------------
__global__ __launch_bounds__(256) void router_kernel(
    const float* __restrict__ x, const float* __restrict__ rw,
    int* __restrict__ cnt, int* __restrict__ rowlist, float* __restrict__ wrow)
{
    int wave = threadIdx.x >> 6;
    int lane = threadIdx.x & 63;
    int t = blockIdx.x * 4 + wave;

    float xv[16];
    const float* xp = x + (size_t)t * HID + lane * 16;
#pragma unroll
    for (int q = 0; q < 4; q++) {
        float4 v = *(const float4*)(xp + q * 4);
        xv[q * 4 + 0] = v.x; xv[q * 4 + 1] = v.y;
        xv[q * 4 + 2] = v.z; xv[q * 4 + 3] = v.w;
    }

    float logit[NE];
#pragma unroll
    for (int e = 0; e < NE; e++) {
        const float* rp = rw + (size_t)e * HID + lane * 16;
        float acc = 0.f;
#pragma unroll
        for (int q = 0; q < 4; q++) {
            float4 v = *(const float4*)(rp + q * 4);
            acc += xv[q * 4 + 0] * v.x + xv[q * 4 + 1] * v.y
                 + xv[q * 4 + 2] * v.z + xv[q * 4 + 3] * v.w;
        }
#pragma unroll
        for (int off = 32; off; off >>= 1) acc += __shfl_xor(acc, off, 64);
        logit[e] = acc;
    }

    if (lane == 0) {
        float v0 = -1e30f; int i0 = 0;
#pragma unroll
        for (int e = 0; e < NE; e++) if (logit[e] > v0) { v0 = logit[e]; i0 = e; }
        float v1 = -1e30f; int i1 = 0;
#pragma unroll
        for (int e = 0; e < NE; e++) if (e != i0 && logit[e] > v1) { v1 = logit[e]; i1 = e; }
        float w0 = 1.0f / (1.0f + __expf(v1 - v0));
        float w1 = 1.0f - w0;
        int p0 = atomicAdd(&cnt[i0], 1);
        rowlist[i0 * T_TOKENS + p0] = t;
        wrow[i0 * T_TOKENS + p0] = w0;
        int p1 = atomicAdd(&cnt[i1], 1);
        rowlist[i1 * T_TOKENS + p1] = t;
        wrow[i1 * T_TOKENS + p1] = w1;
    }
}

// ---------------- offsets: exclusive scan over 8 counts ----------------
__global__ void offsets_kernel(const int* __restrict__ cnt, int* __restrict__ off)
{
    if (threadIdx.x == 0) {
        int s = 0;
        for (int e = 0; e < NE; e++) { off[e] = s; s += cnt[e]; }
    }
}

// ---------------- convert fp32 -> bf16 (flat) ----------------
__global__ __launch_bounds__(256) void convert_kernel(
    const float* __restrict__ in, u16* __restrict__ out)
{
    int i = (blockIdx.x * 256 + threadIdx.x) * 8;
    float4 a = *(const float4*)(in + i);
    float4 b = *(const float4*)(in + i + 4);
    u16 r[8] = { f2bf(a.x), f2bf(a.y), f2bf(a.z), f2bf(a.w),
                 f2bf(b.x), f2bf(b.y), f2bf(b.z), f2bf(b.w) };
    *(uint4*)(out + i) = *(const uint4*)r;
}

// ------- convert+transpose: fp32 [E][K][N] -> bf16 [E][N][K] -------
// 64x64 tiles. Load coalesced along n, write coalesced along k.
__global__ __launch_bounds__(256) void convtrans_kernel(
    const float* __restrict__ in, u16* __restrict__ outp, int K, int N)
{
    __shared__ u16 tile[64][72];   // [n][k], pad 72 (144B stride = +4 banks/row)
    int e = blockIdx.z;
    const float* ip = in + (size_t)e * K * N;
    u16* op = outp + (size_t)e * K * N;
    int n0 = blockIdx.x * 64, k0 = blockIdx.y * 64;
    int t = threadIdx.x;

    int k = t >> 2;               // 0..63
    int nq = (t & 3) * 16;        // 0,16,32,48
    const float* src = ip + (size_t)(k0 + k) * N + n0 + nq;
#pragma unroll
    for (int q = 0; q < 4; q++) {
        float4 v = *(const float4*)(src + q * 4);
        tile[nq + q * 4 + 0][k] = f2bf(v.x);
        tile[nq + q * 4 + 1][k] = f2bf(v.y);
        tile[nq + q * 4 + 2][k] = f2bf(v.z);
        tile[nq + q * 4 + 3][k] = f2bf(v.w);
    }
    __syncthreads();

    int n = t >> 2;               // 0..63
    int kq = (t & 3) * 16;        // 0,16,32,48
    u16* dst = op + (size_t)(n0 + n) * K + k0 + kq;
    *(uint4*)(dst + 0) = *(const uint4*)&tile[n][kq + 0];
    *(uint4*)(dst + 8) = *(const uint4*)&tile[n][kq + 8];
}

#define BM 128
#define BN 128
#define BK 64
#define LDK 72

// ---------------- grouped GEMM1: h = gelu(X_gather @ W1t[e]^T) ----------------
// xb bf16 [T][1024]; w1t bf16 [E][N=2048][K=1024] (k-contiguous).
__global__ __launch_bounds__(256) void gemm1_kernel(
    const u16* __restrict__ xb, const u16* __restrict__ w1t,
    const int* __restrict__ cnt, const int* __restrict__ off,
    const int* __restrict__ rowlist, u16* __restrict__ hbuf)
{
    int e = blockIdx.z;
    int n_e = cnt[e];
    int mt = blockIdx.x;
    if (mt * BM >= n_e) return;
    int nt = blockIdx.y;

    __shared__ u16 As[BM][LDK];
    __shared__ u16 Bs[BN][LDK];
    __shared__ int toks[BM];

    int tid = threadIdx.x;
    if (tid < BM) {
        int r = mt * BM + tid;
        toks[tid] = (r < n_e) ? rowlist[e * T_TOKENS + r] : 0;
    }
    __syncthreads();

    int wv = tid >> 6, lane = tid & 63;
    int wm = (wv & 1) * 64, wn = (wv >> 1) * 64;
    int l15 = lane & 15, l4 = lane >> 4;

    f32x4 acc[4][4];
#pragma unroll
    for (int i = 0; i < 4; i++)
#pragma unroll
        for (int j = 0; j < 4; j++) acc[i][j] = (f32x4){0.f, 0.f, 0.f, 0.f};

    const u16* w1e = w1t + ((size_t)e * HID2 + nt * BN) * HID;   // row n: + n*HID + k

    for (int kb = 0; kb < HID; kb += BK) {
#pragma unroll
        for (int i = 0; i < 4; i++) {
            int idx = tid + i * 256;            // 0..1023
            int m = idx >> 3;                   // 0..127
            int kk = (idx & 7) * 8;             // 0..56
            *(uint4*)&As[m][kk] = *(const uint4*)(xb + (size_t)toks[m] * HID + kb + kk);
            *(uint4*)&Bs[m][kk] = *(const uint4*)(w1e + (size_t)m * HID + kb + kk);
        }
        __syncthreads();
#pragma unroll
        for (int ks = 0; ks < 2; ks++) {
            int kk = ks * 32 + l4 * 8;
            bf16x8 af[4], bfr[4];
#pragma unroll
            for (int i = 0; i < 4; i++) af[i] = *(const bf16x8*)&As[wm + i * 16 + l15][kk];
#pragma unroll
            for (int j = 0; j < 4; j++) bfr[j] = *(const bf16x8*)&Bs[wn + j * 16 + l15][kk];
#pragma unroll
            for (int i = 0; i < 4; i++)
#pragma unroll
                for (int j = 0; j < 4; j++)
                    acc[i][j] = __builtin_amdgcn_mfma_f32_16x16x32_bf16(af[i], bfr[j], acc[i][j], 0, 0, 0);
        }
        __syncthreads();
    }

    int base_row = off[e] + mt * BM;
#pragma unroll
    for (int i = 0; i < 4; i++) {
        int mlo = wm + i * 16 + l4 * 4;
#pragma unroll
        for (int j = 0; j < 4; j++) {
            int n = nt * BN + wn + j * 16 + l15;
#pragma unroll
            for (int rg = 0; rg < 4; rg++) {
                int m = mlo + rg;
                int r = mt * BM + m;
                if (r < n_e) {
                    float v = acc[i][j][rg];
                    float g = 0.5f * v * (1.0f + erff(v * 0.70710678118654752f));
                    hbuf[(size_t)(base_row + m) * HID2 + n] = f2bf(g);
                }
            }
        }
    }
}

// ---------------- grouped GEMM2: d_out += w * (H @ W2t[e]^T) ----------------
// hbuf bf16 [rows][2048]; w2t bf16 [E][N=1024][K=2048] (k-contiguous).
__global__ __launch_bounds__(256) void gemm2_kernel(
    const u16* __restrict__ hbuf, const u16* __restrict__ w2t,
    const int* __restrict__ cnt, const int* __restrict__ off,
    const int* __restrict__ rowlist, const float* __restrict__ wrow,
    float* __restrict__ dout)
{
    int e = blockIdx.z;
    int n_e = cnt[e];
    int mt = blockIdx.x;
    if (mt * BM >= n_e) return;
    int nt = blockIdx.y;

    __shared__ u16 As[BM][LDK];
    __shared__ u16 Bs[BN][LDK];
    __shared__ int toks[BM];
    __shared__ float wts[BM];

    int tid = threadIdx.x;
    if (tid < BM) {
        int r = mt * BM + tid;
        toks[tid] = (r < n_e) ? rowlist[e * T_TOKENS + r] : 0;
        wts[tid] = (r < n_e) ? wrow[e * T_TOKENS + r] : 0.f;
    }
    __syncthreads();

    int wv = tid >> 6, lane = tid & 63;
    int wm = (wv & 1) * 64, wn = (wv >> 1) * 64;
    int l15 = lane & 15, l4 = lane >> 4;

    f32x4 acc[4][4];
#pragma unroll
    for (int i = 0; i < 4; i++)
#pragma unroll
        for (int j = 0; j < 4; j++) acc[i][j] = (f32x4){0.f, 0.f, 0.f, 0.f};

    const u16* hrow = hbuf + (size_t)(off[e] + mt * BM) * HID2;
    const u16* w2e = w2t + ((size_t)e * HID + nt * BN) * HID2;   // row n: + n*HID2 + k

    for (int kb = 0; kb < HID2; kb += BK) {
#pragma unroll
        for (int i = 0; i < 4; i++) {
            int idx = tid + i * 256;
            int m = idx >> 3;
            int kk = (idx & 7) * 8;
            *(uint4*)&As[m][kk] = *(const uint4*)(hrow + (size_t)m * HID2 + kb + kk);
            *(uint4*)&Bs[m][kk] = *(const uint4*)(w2e + (size_t)m * HID2 + kb + kk);
        }
        __syncthreads();
#pragma unroll
        for (int ks = 0; ks < 2; ks++) {
            int kk = ks * 32 + l4 * 8;
            bf16x8 af[4], bfr[4];
#pragma unroll
            for (int i = 0; i < 4; i++) af[i] = *(const bf16x8*)&As[wm + i * 16 + l15][kk];
#pragma unroll
            for (int j = 0; j < 4; j++) bfr[j] = *(const bf16x8*)&Bs[wn + j * 16 + l15][kk];
#pragma unroll
            for (int i = 0; i < 4; i++)
#pragma unroll
                for (int j = 0; j < 4; j++)
                    acc[i][j] = __builtin_amdgcn_mfma_f32_16x16x32_bf16(af[i], bfr[j], acc[i][j], 0, 0, 0);
        }
        __syncthreads();
    }

#pragma unroll
    for (int i = 0; i < 4; i++) {
        int mlo = wm + i * 16 + l4 * 4;
#pragma unroll
        for (int j = 0; j < 4; j++) {
            int n = nt * BN + wn + j * 16 + l15;
#pragma unroll
            for (int rg = 0; rg < 4; rg++) {
                int m = mlo + rg;
                int r = mt * BM + m;
                if (r < n_e) {
                    atomicAdd(&dout[(size_t)toks[m] * HID + n], acc[i][j][rg] * wts[m]);
                }
            }
        }
    }
}

extern "C" void kernel_launch(void* const* d_in, const int* in_sizes, int n_in,
                              void* d_out, int out_size, void* d_ws, size_t ws_size,
                              hipStream_t stream)
{
    const float* x  = (const float*)d_in[0];   // [8192][1024] fp32
    const float* rw = (const float*)d_in[1];   // [8][1024] fp32
    const float* w1 = (const float*)d_in[2];   // [8][1024][2048] fp32
    const float* w2 = (const float*)d_in[3];   // [8][2048][1024] fp32
    float* out = (float*)d_out;                // [8192][1024] fp32

    // Workspace (~113 MiB): control | xb 16MB | wt 32MB (w1t then w2t) | hbuf 64MB
    char* ws = (char*)d_ws;
    int*   cnt     = (int*)(ws + 0);
    int*   off     = (int*)(ws + 256);
    int*   rowlist = (int*)(ws + 512);                                  // 256 KB
    float* wrow    = (float*)(ws + 512 + (size_t)NE * T_TOKENS * 4);    // 256 KB
    u16*   xb      = (u16*)(ws + (1u << 20));                           // 16 MiB
    u16*   wt      = (u16*)(ws + (17u << 20));                          // 32 MiB (shared)
    u16*   hbuf    = (u16*)(ws + (49u << 20));                          // 64 MiB

    hipMemsetAsync(cnt, 0, 32, stream);
    hipMemsetAsync(out, 0, (size_t)T_TOKENS * HID * sizeof(float), stream);

    convert_kernel<<<T_TOKENS * HID / 8 / 256, 256, 0, stream>>>(x, xb);
    router_kernel<<<T_TOKENS / 4, 256, 0, stream>>>(x, rw, cnt, rowlist, wrow);
    offsets_kernel<<<1, 64, 0, stream>>>(cnt, off);

    // w1 [E][K=1024][N=2048] -> wt [E][N=2048][K=1024]
    convtrans_kernel<<<dim3(HID2 / 64, HID / 64, NE), 256, 0, stream>>>(w1, wt, HID, HID2);
    gemm1_kernel<<<dim3(T_TOKENS / BM, HID2 / BN, NE), 256, 0, stream>>>(xb, wt, cnt, off, rowlist, hbuf);

    // w2 [E][K=2048][N=1024] -> wt [E][N=1024][K=2048]  (reuses wt after gemm1)
    convtrans_kernel<<<dim3(HID / 64, HID2 / 64, NE), 256, 0, stream>>>(w2, wt, HID2, HID);
    gemm2_kernel<<<dim3(T_TOKENS / BM, HID / BN, NE), 256, 0, stream>>>(hbuf, wt, cnt, off, rowlist, wrow, out);
}

// Round 5
// 713.018 us; speedup vs baseline: 1.4710x; 1.1784x over previous
//
#include <hip/hip_runtime.h>
#include <cstdint>
#include <cstddef>

#define T_TOKENS 8192
#define HID 1024
#define HID2 2048
#define NE 8

typedef unsigned short u16;
typedef unsigned int u32;
typedef __bf16 bf16x8 __attribute__((ext_vector_type(8)));
typedef float f32x4 __attribute__((ext_vector_type(4)));

__device__ __forceinline__ float bf2f(u16 u) {
    union { u32 i; float f; } x; x.i = ((u32)u) << 16; return x.f;
}
__device__ __forceinline__ u16 f2bf(float f) {
    union { float f; u32 i; } x; x.f = f;
    u32 r = x.i + 0x7fffu + ((x.i >> 16) & 1u);   // RNE
    return (u16)(r >> 16);
}

// async 16B global -> LDS (lane-ordered dest: base + lane*16)
__device__ __forceinline__ void cp16(const void* g, void* l) {
    __builtin_amdgcn_global_load_lds(
        (const __attribute__((address_space(1))) u32*)g,
        (__attribute__((address_space(3))) u32*)l,
        16, 0, 0);
}

// tanh-approx GELU: v / (1 + exp(-1.59577*(v + 0.044715 v^3))) ; |err|<~3e-4
__device__ __forceinline__ float gelu_f(float v) {
    float v2 = v * v;
    float t = fmaf(0.0713548162726f, v2, 1.59576912161f);
    float d = 1.0f + __expf(-v * t);
    return v * __builtin_amdgcn_rcpf(d);
}

// ---------------- router: one wave per token, full fp32 ----------------
__global__ __launch_bounds__(256) void router_kernel(
    const float* __restrict__ x, const float* __restrict__ rw,
    int* __restrict__ cnt, int* __restrict__ rowlist,
    int* __restrict__ tok_slots, float* __restrict__ tok_w)
{
    int wave = threadIdx.x >> 6;
    int lane = threadIdx.x & 63;
    int t = blockIdx.x * 4 + wave;

    float xv[16];
    const float* xp = x + (size_t)t * HID + lane * 16;
#pragma unroll
    for (int q = 0; q < 4; q++) {
        float4 v = *(const float4*)(xp + q * 4);
        xv[q * 4 + 0] = v.x; xv[q * 4 + 1] = v.y;
        xv[q * 4 + 2] = v.z; xv[q * 4 + 3] = v.w;
    }

    float logit[NE];
#pragma unroll
    for (int e = 0; e < NE; e++) {
        const float* rp = rw + (size_t)e * HID + lane * 16;
        float acc = 0.f;
#pragma unroll
        for (int q = 0; q < 4; q++) {
            float4 v = *(const float4*)(rp + q * 4);
            acc += xv[q * 4 + 0] * v.x + xv[q * 4 + 1] * v.y
                 + xv[q * 4 + 2] * v.z + xv[q * 4 + 3] * v.w;
        }
#pragma unroll
        for (int off = 32; off; off >>= 1) acc += __shfl_xor(acc, off, 64);
        logit[e] = acc;
    }

    if (lane == 0) {
        float v0 = -1e30f; int i0 = 0;
#pragma unroll
        for (int e = 0; e < NE; e++) if (logit[e] > v0) { v0 = logit[e]; i0 = e; }
        float v1 = -1e30f; int i1 = 0;
#pragma unroll
        for (int e = 0; e < NE; e++) if (e != i0 && logit[e] > v1) { v1 = logit[e]; i1 = e; }
        float w0 = 1.0f / (1.0f + __expf(v1 - v0));
        float w1 = 1.0f - w0;
        int p0 = atomicAdd(&cnt[i0], 1);
        rowlist[i0 * T_TOKENS + p0] = t;
        int p1 = atomicAdd(&cnt[i1], 1);
        rowlist[i1 * T_TOKENS + p1] = t;
        tok_slots[t * 2 + 0] = (i0 << 16) | p0;
        tok_slots[t * 2 + 1] = (i1 << 16) | p1;
        tok_w[t * 2 + 0] = w0;
        tok_w[t * 2 + 1] = w1;
    }
}

// ---------------- offsets: exclusive scan over 8 counts ----------------
__global__ void offsets_kernel(const int* __restrict__ cnt, int* __restrict__ off)
{
    if (threadIdx.x == 0) {
        int s = 0;
        for (int e = 0; e < NE; e++) { off[e] = s; s += cnt[e]; }
    }
}

// ---------------- convert fp32 -> bf16 (flat) ----------------
__global__ __launch_bounds__(256) void convert_kernel(
    const float* __restrict__ in, u16* __restrict__ out)
{
    int i = (blockIdx.x * 256 + threadIdx.x) * 8;
    float4 a = *(const float4*)(in + i);
    float4 b = *(const float4*)(in + i + 4);
    u16 r[8] = { f2bf(a.x), f2bf(a.y), f2bf(a.z), f2bf(a.w),
                 f2bf(b.x), f2bf(b.y), f2bf(b.z), f2bf(b.w) };
    *(uint4*)(out + i) = *(const uint4*)r;
}

// ------- convert+transpose: fp32 [E][K][N] -> bf16 [E][N][K] -------
__global__ __launch_bounds__(256) void convtrans_kernel(
    const float* __restrict__ in, u16* __restrict__ outp, int K, int N)
{
    __shared__ u16 tile[64][72];
    int e = blockIdx.z;
    const float* ip = in + (size_t)e * K * N;
    u16* op = outp + (size_t)e * K * N;
    int n0 = blockIdx.x * 64, k0 = blockIdx.y * 64;
    int t = threadIdx.x;

    int k = t >> 2;
    int nq = (t & 3) * 16;
    const float* src = ip + (size_t)(k0 + k) * N + n0 + nq;
#pragma unroll
    for (int q = 0; q < 4; q++) {
        float4 v = *(const float4*)(src + q * 4);
        tile[nq + q * 4 + 0][k] = f2bf(v.x);
        tile[nq + q * 4 + 1][k] = f2bf(v.y);
        tile[nq + q * 4 + 2][k] = f2bf(v.z);
        tile[nq + q * 4 + 3][k] = f2bf(v.w);
    }
    __syncthreads();

    int n = t >> 2;
    int kq = (t & 3) * 16;
    u16* dst = op + (size_t)(n0 + n) * K + k0 + kq;
    *(uint4*)(dst + 0) = *(const uint4*)&tile[n][kq + 0];
    *(uint4*)(dst + 8) = *(const uint4*)&tile[n][kq + 8];
}

#define BM 128
#define BN 128
#define BK 64

// ---------------- grouped GEMM1: h = gelu(X_gather @ W1t[e]^T) ----------------
// xb bf16 [T][1024]; w1t bf16 [E][2048][1024] k-contig. LDS unpadded [128][64]
// with XOR chunk swizzle (chunk ^= row&7) applied on the global source side.
__global__ __launch_bounds__(256) void gemm1_kernel(
    const u16* __restrict__ xb, const u16* __restrict__ w1t,
    const int* __restrict__ cnt, const int* __restrict__ off,
    const int* __restrict__ rowlist, u16* __restrict__ hbuf)
{
    int e = blockIdx.z;
    int n_e = cnt[e];
    int mt = blockIdx.x;
    if (mt * BM >= n_e) return;
    int nt = blockIdx.y;

    __shared__ u16 As[BM * BK];
    __shared__ u16 Bs[BN * BK];
    __shared__ int toks[BM];

    int tid = threadIdx.x;
    if (tid < BM) {
        int r = mt * BM + tid;
        toks[tid] = (r < n_e) ? rowlist[e * T_TOKENS + r] : 0;
    }
    __syncthreads();

    int wv = tid >> 6, lane = tid & 63;
    int wm = (wv & 1) * 64, wn = (wv >> 1) * 64;
    int l15 = lane & 15, l4 = lane >> 4;
    int sr = lane >> 3, sc = lane & 7;

    const u16* w1e = w1t + ((size_t)e * HID2 + nt * BN) * HID;

    // precompute staging pointers (loop-invariant)
    const u16* aptr[4]; const u16* bptr[4];
    u16* adst[4]; u16* bdst[4];
#pragma unroll
    for (int i = 0; i < 4; i++) {
        int m = wv * 32 + i * 8 + sr;
        int gq = sc ^ (m & 7);
        aptr[i] = xb + (size_t)toks[m] * HID + gq * 8;
        adst[i] = &As[m * BK + sc * 8];
        bptr[i] = w1e + (size_t)m * HID + gq * 8;
        bdst[i] = &Bs[m * BK + sc * 8];
    }

    f32x4 acc[4][4];
#pragma unroll
    for (int i = 0; i < 4; i++)
#pragma unroll
        for (int j = 0; j < 4; j++) acc[i][j] = (f32x4){0.f, 0.f, 0.f, 0.f};

    for (int kb = 0; kb < HID; kb += BK) {
#pragma unroll
        for (int i = 0; i < 4; i++) {
            cp16(aptr[i] + kb, adst[i]);
            cp16(bptr[i] + kb, bdst[i]);
        }
        __syncthreads();
#pragma unroll
        for (int ks = 0; ks < 2; ks++) {
            bf16x8 af[4], bfr[4];
            int q = ks * 4 + l4;
#pragma unroll
            for (int i = 0; i < 4; i++) {
                int ra = wm + i * 16 + l15;
                af[i] = *(const bf16x8*)&As[ra * BK + ((q ^ (ra & 7)) << 3)];
                int rb = wn + i * 16 + l15;
                bfr[i] = *(const bf16x8*)&Bs[rb * BK + ((q ^ (rb & 7)) << 3)];
            }
#pragma unroll
            for (int i = 0; i < 4; i++)
#pragma unroll
                for (int j = 0; j < 4; j++)
                    acc[i][j] = __builtin_amdgcn_mfma_f32_16x16x32_bf16(bfr[j], af[i], acc[i][j], 0, 0, 0);
        }
        __syncthreads();
    }

    // acc[i][j] lane regs: m = wm+i*16+l15 (fixed/lane), n = wn+j*16+l4*4+rg
    int base_row = off[e] + mt * BM;
#pragma unroll
    for (int i = 0; i < 4; i++) {
        int m = wm + i * 16 + l15;
        int r = mt * BM + m;
        if (r < n_e) {
            u16* orow = hbuf + (size_t)(base_row + m) * HID2 + nt * BN + wn + l4 * 4;
#pragma unroll
            for (int j = 0; j < 4; j++) {
                u16 p[4];
#pragma unroll
                for (int rg = 0; rg < 4; rg++) p[rg] = f2bf(gelu_f(acc[i][j][rg]));
                *(uint2*)(orow + j * 16) = *(const uint2*)p;
            }
        }
    }
}

// ---------------- grouped GEMM2: ybuf = H @ W2t[e]^T (bf16, unweighted) ----
__global__ __launch_bounds__(256) void gemm2_kernel(
    const u16* __restrict__ hbuf, const u16* __restrict__ w2t,
    const int* __restrict__ cnt, const int* __restrict__ off,
    u16* __restrict__ ybuf)
{
    int e = blockIdx.z;
    int n_e = cnt[e];
    int mt = blockIdx.x;
    if (mt * BM >= n_e) return;
    int nt = blockIdx.y;

    __shared__ u16 As[BM * BK];
    __shared__ u16 Bs[BN * BK];

    int tid = threadIdx.x;
    int wv = tid >> 6, lane = tid & 63;
    int wm = (wv & 1) * 64, wn = (wv >> 1) * 64;
    int l15 = lane & 15, l4 = lane >> 4;
    int sr = lane >> 3, sc = lane & 7;

    const u16* hrow = hbuf + (size_t)(off[e] + mt * BM) * HID2;
    const u16* w2e = w2t + ((size_t)e * HID + nt * BN) * HID2;

    const u16* aptr[4]; const u16* bptr[4];
    u16* adst[4]; u16* bdst[4];
#pragma unroll
    for (int i = 0; i < 4; i++) {
        int m = wv * 32 + i * 8 + sr;
        int gq = sc ^ (m & 7);
        aptr[i] = hrow + (size_t)m * HID2 + gq * 8;
        adst[i] = &As[m * BK + sc * 8];
        bptr[i] = w2e + (size_t)m * HID2 + gq * 8;
        bdst[i] = &Bs[m * BK + sc * 8];
    }

    f32x4 acc[4][4];
#pragma unroll
    for (int i = 0; i < 4; i++)
#pragma unroll
        for (int j = 0; j < 4; j++) acc[i][j] = (f32x4){0.f, 0.f, 0.f, 0.f};

    for (int kb = 0; kb < HID2; kb += BK) {
#pragma unroll
        for (int i = 0; i < 4; i++) {
            cp16(aptr[i] + kb, adst[i]);
            cp16(bptr[i] + kb, bdst[i]);
        }
        __syncthreads();
#pragma unroll
        for (int ks = 0; ks < 2; ks++) {
            bf16x8 af[4], bfr[4];
            int q = ks * 4 + l4;
#pragma unroll
            for (int i = 0; i < 4; i++) {
                int ra = wm + i * 16 + l15;
                af[i] = *(const bf16x8*)&As[ra * BK + ((q ^ (ra & 7)) << 3)];
                int rb = wn + i * 16 + l15;
                bfr[i] = *(const bf16x8*)&Bs[rb * BK + ((q ^ (rb & 7)) << 3)];
            }
#pragma unroll
            for (int i = 0; i < 4; i++)
#pragma unroll
                for (int j = 0; j < 4; j++)
                    acc[i][j] = __builtin_amdgcn_mfma_f32_16x16x32_bf16(bfr[j], af[i], acc[i][j], 0, 0, 0);
        }
        __syncthreads();
    }

    int base_row = off[e] + mt * BM;
#pragma unroll
    for (int i = 0; i < 4; i++) {
        int m = wm + i * 16 + l15;
        int r = mt * BM + m;
        if (r < n_e) {
            u16* orow = ybuf + (size_t)(base_row + m) * HID + nt * BN + wn + l4 * 4;
#pragma unroll
            for (int j = 0; j < 4; j++) {
                u16 p[4];
#pragma unroll
                for (int rg = 0; rg < 4; rg++) p[rg] = f2bf(acc[i][j][rg]);
                *(uint2*)(orow + j * 16) = *(const uint2*)p;
            }
        }
    }
}

// ---------------- combine: out[t] = w0*y[r0] + w1*y[r1] ----------------
__global__ __launch_bounds__(256) void combine_kernel(
    const u16* __restrict__ ybuf, const int* __restrict__ off,
    const int* __restrict__ tok_slots, const float* __restrict__ tok_w,
    float* __restrict__ out)
{
    int tid = threadIdx.x;
    int t = blockIdx.x * 2 + (tid >> 7);
    int c = (tid & 127) * 8;
    int s0 = tok_slots[t * 2], s1 = tok_slots[t * 2 + 1];
    float w0 = tok_w[t * 2], w1 = tok_w[t * 2 + 1];
    int r0 = off[s0 >> 16] + (s0 & 0xFFFF);
    int r1 = off[s1 >> 16] + (s1 & 0xFFFF);
    uint4 a = *(const uint4*)(ybuf + (size_t)r0 * HID + c);
    uint4 b = *(const uint4*)(ybuf + (size_t)r1 * HID + c);
    const u16* pa = (const u16*)&a;
    const u16* pb = (const u16*)&b;
    float o[8];
#pragma unroll
    for (int q = 0; q < 8; q++) o[q] = w0 * bf2f(pa[q]) + w1 * bf2f(pb[q]);
    *(float4*)(out + (size_t)t * HID + c) = *(const float4*)&o[0];
    *(float4*)(out + (size_t)t * HID + c + 4) = *(const float4*)&o[4];
}

extern "C" void kernel_launch(void* const* d_in, const int* in_sizes, int n_in,
                              void* d_out, int out_size, void* d_ws, size_t ws_size,
                              hipStream_t stream)
{
    const float* x  = (const float*)d_in[0];   // [8192][1024] fp32
    const float* rw = (const float*)d_in[1];   // [8][1024] fp32
    const float* w1 = (const float*)d_in[2];   // [8][1024][2048] fp32
    const float* w2 = (const float*)d_in[3];   // [8][2048][1024] fp32
    float* out = (float*)d_out;                // [8192][1024] fp32

    // Workspace (~146 MiB): control | xb 16M | wt 32M | hbuf 64.5M | ybuf 32M
    char* ws = (char*)d_ws;
    int*   cnt       = (int*)(ws + 0);
    int*   off       = (int*)(ws + 256);
    int*   rowlist   = (int*)(ws + 512);                              // 256 KiB
    int*   tok_slots = (int*)(ws + 512 + 262144);                     // 64 KiB
    float* tok_w     = (float*)(ws + 512 + 262144 + 65536);           // 64 KiB
    u16*   xb        = (u16*)(ws + (1ull << 20));                     // 16 MiB
    u16*   wt        = (u16*)(ws + (17ull << 20));                    // 32 MiB
    u16*   hbuf      = (u16*)(ws + (49ull << 20));                    // 64.5 MiB (16512 rows)
    u16*   ybuf      = (u16*)(ws + (114ull << 20));                   // 32 MiB (16384 rows)

    hipMemsetAsync(cnt, 0, 32, stream);

    convert_kernel<<<T_TOKENS * HID / 8 / 256, 256, 0, stream>>>(x, xb);
    router_kernel<<<T_TOKENS / 4, 256, 0, stream>>>(x, rw, cnt, rowlist, tok_slots, tok_w);
    offsets_kernel<<<1, 64, 0, stream>>>(cnt, off);

    // w1 [E][1024][2048] -> wt [E][2048][1024]
    convtrans_kernel<<<dim3(HID2 / 64, HID / 64, NE), 256, 0, stream>>>(w1, wt, HID, HID2);
    gemm1_kernel<<<dim3(T_TOKENS / BM, HID2 / BN, NE), 256, 0, stream>>>(xb, wt, cnt, off, rowlist, hbuf);

    // w2 [E][2048][1024] -> wt [E][1024][2048]
    convtrans_kernel<<<dim3(HID / 64, HID2 / 64, NE), 256, 0, stream>>>(w2, wt, HID2, HID);
    gemm2_kernel<<<dim3(T_TOKENS / BM, HID / BN, NE), 256, 0, stream>>>(hbuf, wt, cnt, off, ybuf);

    combine_kernel<<<T_TOKENS / 2, 256, 0, stream>>>(ybuf, off, tok_slots, tok_w, out);
}

// Round 6
// 542.773 us; speedup vs baseline: 1.9323x; 1.3137x over previous
//
#include <hip/hip_runtime.h>
#include <cstdint>
#include <cstddef>

#define T_TOKENS 8192
#define HID 1024
#define HID2 2048
#define NE 8

typedef unsigned short u16;
typedef unsigned int u32;
typedef __bf16 bf16x8 __attribute__((ext_vector_type(8)));
typedef float f32x4 __attribute__((ext_vector_type(4)));

__device__ __forceinline__ float bf2f(u16 u) {
    union { u32 i; float f; } x; x.i = ((u32)u) << 16; return x.f;
}
__device__ __forceinline__ u16 f2bf(float f) {
    union { float f; u32 i; } x; x.f = f;
    u32 r = x.i + 0x7fffu + ((x.i >> 16) & 1u);   // RNE
    return (u16)(r >> 16);
}

// async 16B global -> LDS (lane-ordered dest: base + lane*16)
__device__ __forceinline__ void cp16(const void* g, void* l) {
    __builtin_amdgcn_global_load_lds(
        (const __attribute__((address_space(1))) u32*)g,
        (__attribute__((address_space(3))) u32*)l,
        16, 0, 0);
}

// tanh-approx GELU: |err| < ~3e-4, buried under bf16 rounding
__device__ __forceinline__ float gelu_f(float v) {
    float v2 = v * v;
    float t = fmaf(0.0713548162726f, v2, 1.59576912161f);
    float d = 1.0f + __expf(-v * t);
    return v * __builtin_amdgcn_rcpf(d);
}

// ---------------- router: 8 tokens/wave, fused x->bf16 convert ----------------
// Lane l: token group tg=l>>3, within-token lane il=l&7; lane covers floats
// il*4 + 32q, q=0..31. Two-level counting: LDS histogram (atomic ret = local
// rank) then one padded global atomic per expert per block (cnt[e*32]).
__global__ __launch_bounds__(256) void router_kernel(
    const float* __restrict__ x, const float* __restrict__ rw,
    u16* __restrict__ xb,
    int* __restrict__ cnt, int* __restrict__ rowlist,
    int* __restrict__ tok_slots, float* __restrict__ tok_w)
{
    __shared__ int lbin[NE];
    __shared__ int gbase[NE];
    int tid = threadIdx.x;
    if (tid < NE) lbin[tid] = 0;
    __syncthreads();

    int wave = tid >> 6;
    int lane = tid & 63;
    int tg = lane >> 3, il = lane & 7;
    int t = blockIdx.x * 32 + wave * 8 + tg;

    const float* xrow = x + (size_t)t * HID;
    u16* xbrow = xb + (size_t)t * HID;

    float acc[NE];
#pragma unroll
    for (int e = 0; e < NE; e++) acc[e] = 0.f;

#pragma unroll 8
    for (int q = 0; q < 32; q++) {
        int c = il * 4 + 32 * q;
        float4 xv = *(const float4*)(xrow + c);
        // fused convert
        u16 p[4] = { f2bf(xv.x), f2bf(xv.y), f2bf(xv.z), f2bf(xv.w) };
        *(uint2*)(xbrow + c) = *(const uint2*)p;
#pragma unroll
        for (int e = 0; e < NE; e++) {
            float4 rv = *(const float4*)(rw + (size_t)e * HID + c);
            acc[e] = fmaf(xv.x, rv.x, acc[e]);
            acc[e] = fmaf(xv.y, rv.y, acc[e]);
            acc[e] = fmaf(xv.z, rv.z, acc[e]);
            acc[e] = fmaf(xv.w, rv.w, acc[e]);
        }
    }
    // reduce across the 8 lanes of each token
#pragma unroll
    for (int e = 0; e < NE; e++) {
        acc[e] += __shfl_xor(acc[e], 1, 64);
        acc[e] += __shfl_xor(acc[e], 2, 64);
        acc[e] += __shfl_xor(acc[e], 4, 64);
    }

    int i0 = 0, i1 = 0, ph0 = 0, ph1 = 0;
    float w0 = 0.f, w1 = 0.f;
    if (il == 0) {
        float v0 = -1e30f;
#pragma unroll
        for (int e = 0; e < NE; e++) if (acc[e] > v0) { v0 = acc[e]; i0 = e; }
        float v1 = -1e30f;
#pragma unroll
        for (int e = 0; e < NE; e++) if (e != i0 && acc[e] > v1) { v1 = acc[e]; i1 = e; }
        w0 = 1.0f / (1.0f + __expf(v1 - v0));
        w1 = 1.0f - w0;
        ph0 = atomicAdd(&lbin[i0], 1);
        ph1 = atomicAdd(&lbin[i1], 1);
    }
    __syncthreads();
    if (tid < NE) gbase[tid] = atomicAdd(&cnt[tid * 32], lbin[tid]);
    __syncthreads();
    if (il == 0) {
        int p0 = gbase[i0] + ph0;
        int p1 = gbase[i1] + ph1;
        rowlist[i0 * T_TOKENS + p0] = t;
        rowlist[i1 * T_TOKENS + p1] = t;
        tok_slots[t * 2 + 0] = (i0 << 16) | p0;
        tok_slots[t * 2 + 1] = (i1 << 16) | p1;
        tok_w[t * 2 + 0] = w0;
        tok_w[t * 2 + 1] = w1;
    }
}

// ------- offsets: exclusive scan over padded counts, also compact -------
__global__ void offsets_kernel(const int* __restrict__ cnt,
                               int* __restrict__ off, int* __restrict__ cntc)
{
    if (threadIdx.x == 0) {
        int s = 0;
        for (int e = 0; e < NE; e++) {
            int c = cnt[e * 32];
            off[e] = s; cntc[e] = c; s += c;
        }
    }
}

// ------- convert+transpose: fp32 [E][K][N] -> bf16 [E][N][K] -------
__global__ __launch_bounds__(256) void convtrans_kernel(
    const float* __restrict__ in, u16* __restrict__ outp, int K, int N)
{
    __shared__ u16 tile[64][72];
    int e = blockIdx.z;
    const float* ip = in + (size_t)e * K * N;
    u16* op = outp + (size_t)e * K * N;
    int n0 = blockIdx.x * 64, k0 = blockIdx.y * 64;
    int t = threadIdx.x;

    int k = t >> 2;
    int nq = (t & 3) * 16;
    const float* src = ip + (size_t)(k0 + k) * N + n0 + nq;
#pragma unroll
    for (int q = 0; q < 4; q++) {
        float4 v = *(const float4*)(src + q * 4);
        tile[nq + q * 4 + 0][k] = f2bf(v.x);
        tile[nq + q * 4 + 1][k] = f2bf(v.y);
        tile[nq + q * 4 + 2][k] = f2bf(v.z);
        tile[nq + q * 4 + 3][k] = f2bf(v.w);
    }
    __syncthreads();

    int n = t >> 2;
    int kq = (t & 3) * 16;
    u16* dst = op + (size_t)(n0 + n) * K + k0 + kq;
    *(uint4*)(dst + 0) = *(const uint4*)&tile[n][kq + 0];
    *(uint4*)(dst + 8) = *(const uint4*)&tile[n][kq + 8];
}

#define BM 128
#define BN 128
#define BK 64

// ---------------- grouped GEMM1: h = gelu(X_gather @ W1t[e]^T) ----------------
__global__ __launch_bounds__(256) void gemm1_kernel(
    const u16* __restrict__ xb, const u16* __restrict__ w1t,
    const int* __restrict__ cntc, const int* __restrict__ off,
    const int* __restrict__ rowlist, u16* __restrict__ hbuf)
{
    int e = blockIdx.z;
    int n_e = cntc[e];
    int mt = blockIdx.x;
    if (mt * BM >= n_e) return;
    int nt = blockIdx.y;

    __shared__ u16 As[BM * BK];
    __shared__ u16 Bs[BN * BK];
    __shared__ int toks[BM];

    int tid = threadIdx.x;
    if (tid < BM) {
        int r = mt * BM + tid;
        toks[tid] = (r < n_e) ? rowlist[e * T_TOKENS + r] : 0;
    }
    __syncthreads();

    int wv = tid >> 6, lane = tid & 63;
    int wm = (wv & 1) * 64, wn = (wv >> 1) * 64;
    int l15 = lane & 15, l4 = lane >> 4;
    int sr = lane >> 3, sc = lane & 7;

    const u16* w1e = w1t + ((size_t)e * HID2 + nt * BN) * HID;

    const u16* aptr[4]; const u16* bptr[4];
    u16* adst[4]; u16* bdst[4];
#pragma unroll
    for (int i = 0; i < 4; i++) {
        int m = wv * 32 + i * 8 + sr;
        int gq = sc ^ (m & 7);
        aptr[i] = xb + (size_t)toks[m] * HID + gq * 8;
        adst[i] = &As[m * BK + sc * 8];
        bptr[i] = w1e + (size_t)m * HID + gq * 8;
        bdst[i] = &Bs[m * BK + sc * 8];
    }

    f32x4 acc[4][4];
#pragma unroll
    for (int i = 0; i < 4; i++)
#pragma unroll
        for (int j = 0; j < 4; j++) acc[i][j] = (f32x4){0.f, 0.f, 0.f, 0.f};

    for (int kb = 0; kb < HID; kb += BK) {
#pragma unroll
        for (int i = 0; i < 4; i++) {
            cp16(aptr[i] + kb, adst[i]);
            cp16(bptr[i] + kb, bdst[i]);
        }
        __syncthreads();
#pragma unroll
        for (int ks = 0; ks < 2; ks++) {
            bf16x8 af[4], bfr[4];
            int q = ks * 4 + l4;
#pragma unroll
            for (int i = 0; i < 4; i++) {
                int ra = wm + i * 16 + l15;
                af[i] = *(const bf16x8*)&As[ra * BK + ((q ^ (ra & 7)) << 3)];
                int rb = wn + i * 16 + l15;
                bfr[i] = *(const bf16x8*)&Bs[rb * BK + ((q ^ (rb & 7)) << 3)];
            }
#pragma unroll
            for (int i = 0; i < 4; i++)
#pragma unroll
                for (int j = 0; j < 4; j++)
                    acc[i][j] = __builtin_amdgcn_mfma_f32_16x16x32_bf16(bfr[j], af[i], acc[i][j], 0, 0, 0);
        }
        __syncthreads();
    }

    int base_row = off[e] + mt * BM;
#pragma unroll
    for (int i = 0; i < 4; i++) {
        int m = wm + i * 16 + l15;
        int r = mt * BM + m;
        if (r < n_e) {
            u16* orow = hbuf + (size_t)(base_row + m) * HID2 + nt * BN + wn + l4 * 4;
#pragma unroll
            for (int j = 0; j < 4; j++) {
                u16 p[4];
#pragma unroll
                for (int rg = 0; rg < 4; rg++) p[rg] = f2bf(gelu_f(acc[i][j][rg]));
                *(uint2*)(orow + j * 16) = *(const uint2*)p;
            }
        }
    }
}

// ---------------- grouped GEMM2: ybuf = H @ W2t[e]^T (bf16, unweighted) ----
__global__ __launch_bounds__(256) void gemm2_kernel(
    const u16* __restrict__ hbuf, const u16* __restrict__ w2t,
    const int* __restrict__ cntc, const int* __restrict__ off,
    u16* __restrict__ ybuf)
{
    int e = blockIdx.z;
    int n_e = cntc[e];
    int mt = blockIdx.x;
    if (mt * BM >= n_e) return;
    int nt = blockIdx.y;

    __shared__ u16 As[BM * BK];
    __shared__ u16 Bs[BN * BK];

    int tid = threadIdx.x;
    int wv = tid >> 6, lane = tid & 63;
    int wm = (wv & 1) * 64, wn = (wv >> 1) * 64;
    int l15 = lane & 15, l4 = lane >> 4;
    int sr = lane >> 3, sc = lane & 7;

    const u16* hrow = hbuf + (size_t)(off[e] + mt * BM) * HID2;
    const u16* w2e = w2t + ((size_t)e * HID + nt * BN) * HID2;

    const u16* aptr[4]; const u16* bptr[4];
    u16* adst[4]; u16* bdst[4];
#pragma unroll
    for (int i = 0; i < 4; i++) {
        int m = wv * 32 + i * 8 + sr;
        int gq = sc ^ (m & 7);
        aptr[i] = hrow + (size_t)m * HID2 + gq * 8;
        adst[i] = &As[m * BK + sc * 8];
        bptr[i] = w2e + (size_t)m * HID2 + gq * 8;
        bdst[i] = &Bs[m * BK + sc * 8];
    }

    f32x4 acc[4][4];
#pragma unroll
    for (int i = 0; i < 4; i++)
#pragma unroll
        for (int j = 0; j < 4; j++) acc[i][j] = (f32x4){0.f, 0.f, 0.f, 0.f};

    for (int kb = 0; kb < HID2; kb += BK) {
#pragma unroll
        for (int i = 0; i < 4; i++) {
            cp16(aptr[i] + kb, adst[i]);
            cp16(bptr[i] + kb, bdst[i]);
        }
        __syncthreads();
#pragma unroll
        for (int ks = 0; ks < 2; ks++) {
            bf16x8 af[4], bfr[4];
            int q = ks * 4 + l4;
#pragma unroll
            for (int i = 0; i < 4; i++) {
                int ra = wm + i * 16 + l15;
                af[i] = *(const bf16x8*)&As[ra * BK + ((q ^ (ra & 7)) << 3)];
                int rb = wn + i * 16 + l15;
                bfr[i] = *(const bf16x8*)&Bs[rb * BK + ((q ^ (rb & 7)) << 3)];
            }
#pragma unroll
            for (int i = 0; i < 4; i++)
#pragma unroll
                for (int j = 0; j < 4; j++)
                    acc[i][j] = __builtin_amdgcn_mfma_f32_16x16x32_bf16(bfr[j], af[i], acc[i][j], 0, 0, 0);
        }
        __syncthreads();
    }

    int base_row = off[e] + mt * BM;
#pragma unroll
    for (int i = 0; i < 4; i++) {
        int m = wm + i * 16 + l15;
        int r = mt * BM + m;
        if (r < n_e) {
            u16* orow = ybuf + (size_t)(base_row + m) * HID + nt * BN + wn + l4 * 4;
#pragma unroll
            for (int j = 0; j < 4; j++) {
                u16 p[4];
#pragma unroll
                for (int rg = 0; rg < 4; rg++) p[rg] = f2bf(acc[i][j][rg]);
                *(uint2*)(orow + j * 16) = *(const uint2*)p;
            }
        }
    }
}

// ---------------- combine: out[t] = w0*y[r0] + w1*y[r1] ----------------
__global__ __launch_bounds__(256) void combine_kernel(
    const u16* __restrict__ ybuf, const int* __restrict__ off,
    const int* __restrict__ tok_slots, const float* __restrict__ tok_w,
    float* __restrict__ out)
{
    int tid = threadIdx.x;
    int t = blockIdx.x * 2 + (tid >> 7);
    int c = (tid & 127) * 8;
    int s0 = tok_slots[t * 2], s1 = tok_slots[t * 2 + 1];
    float w0 = tok_w[t * 2], w1 = tok_w[t * 2 + 1];
    int r0 = off[s0 >> 16] + (s0 & 0xFFFF);
    int r1 = off[s1 >> 16] + (s1 & 0xFFFF);
    uint4 a = *(const uint4*)(ybuf + (size_t)r0 * HID + c);
    uint4 b = *(const uint4*)(ybuf + (size_t)r1 * HID + c);
    const u16* pa = (const u16*)&a;
    const u16* pb = (const u16*)&b;
    float o[8];
#pragma unroll
    for (int q = 0; q < 8; q++) o[q] = w0 * bf2f(pa[q]) + w1 * bf2f(pb[q]);
    *(float4*)(out + (size_t)t * HID + c) = *(const float4*)&o[0];
    *(float4*)(out + (size_t)t * HID + c + 4) = *(const float4*)&o[4];
}

extern "C" void kernel_launch(void* const* d_in, const int* in_sizes, int n_in,
                              void* d_out, int out_size, void* d_ws, size_t ws_size,
                              hipStream_t stream)
{
    const float* x  = (const float*)d_in[0];   // [8192][1024] fp32
    const float* rw = (const float*)d_in[1];   // [8][1024] fp32
    const float* w1 = (const float*)d_in[2];   // [8][1024][2048] fp32
    const float* w2 = (const float*)d_in[3];   // [8][2048][1024] fp32
    float* out = (float*)d_out;                // [8192][1024] fp32

    // Workspace (~146 MiB): control | xb 16M | wt 32M | hbuf 64.5M | ybuf 32M
    char* ws = (char*)d_ws;
    int*   cnt       = (int*)(ws + 0);            // 8 counters, 128B apart (1 KiB)
    int*   off       = (int*)(ws + 1024);
    int*   cntc      = (int*)(ws + 1088);
    int*   rowlist   = (int*)(ws + 2048);                             // 256 KiB
    int*   tok_slots = (int*)(ws + 2048 + 262144);                    // 64 KiB
    float* tok_w     = (float*)(ws + 2048 + 262144 + 65536);          // 64 KiB
    u16*   xb        = (u16*)(ws + (1ull << 20));                     // 16 MiB
    u16*   wt        = (u16*)(ws + (17ull << 20));                    // 32 MiB
    u16*   hbuf      = (u16*)(ws + (49ull << 20));                    // 64.5 MiB
    u16*   ybuf      = (u16*)(ws + (114ull << 20));                   // 32 MiB

    hipMemsetAsync(cnt, 0, 1024, stream);

    router_kernel<<<T_TOKENS / 32, 256, 0, stream>>>(x, rw, xb, cnt, rowlist, tok_slots, tok_w);
    offsets_kernel<<<1, 64, 0, stream>>>(cnt, off, cntc);

    // w1 [E][1024][2048] -> wt [E][2048][1024]
    convtrans_kernel<<<dim3(HID2 / 64, HID / 64, NE), 256, 0, stream>>>(w1, wt, HID, HID2);
    gemm1_kernel<<<dim3(T_TOKENS / BM, HID2 / BN, NE), 256, 0, stream>>>(xb, wt, cntc, off, rowlist, hbuf);

    // w2 [E][2048][1024] -> wt [E][1024][2048]
    convtrans_kernel<<<dim3(HID / 64, HID2 / 64, NE), 256, 0, stream>>>(w2, wt, HID2, HID);
    gemm2_kernel<<<dim3(T_TOKENS / BM, HID / BN, NE), 256, 0, stream>>>(hbuf, wt, cntc, off, ybuf);

    combine_kernel<<<T_TOKENS / 2, 256, 0, stream>>>(ybuf, off, tok_slots, tok_w, out);
}